// Round 2
// baseline (1098.571 us; speedup 1.0000x reference)
//
#include <hip/hip_runtime.h>
#include <math.h>

#define F_IN 128
#define HID  64
#define NH   4
#define DD   16
#define CC   16
#define CSTE 1e-5f

typedef _Float16 half4 __attribute__((ext_vector_type(4)));

__device__ inline float4 reduce16(float4 p) {
    // reduce across the 16 lanes that share (lane & 3), i.e. over bits 2..5
    #pragma unroll
    for (int m = 4; m <= 32; m <<= 1) {
        p.x += __shfl_xor(p.x, m, 64);
        p.y += __shfl_xor(p.y, m, 64);
        p.z += __shfl_xor(p.z, m, 64);
        p.w += __shfl_xor(p.w, m, 64);
    }
    return p;
}

// ---------------- gamma precompute (16 floats) ----------------
__global__ void gamma_kernel(const float* __restrict__ hopwise,
                             const float* __restrict__ temp,
                             float* __restrict__ gam) {
    if (threadIdx.x == 0 && blockIdx.x == 0) {
        for (int h = 0; h < NH; ++h) gam[h * 4 + 0] = temp[h * 4 + 0]; // hop0: raw temp
        for (int hop = 1; hop <= 3; ++hop) {
            float m = -1e30f;
            for (int h = 0; h < NH; ++h) m = fmaxf(m, temp[h * 4 + hop]);
            float e[NH], s = 0.f;
            for (int h = 0; h < NH; ++h) { e[h] = expf(temp[h * 4 + hop] - m); s += e[h]; }
            for (int h = 0; h < NH; ++h) gam[h * 4 + hop] = hopwise[hop] * e[h] / s;
        }
    }
}

// ---------------- CSR build ----------------
__global__ void count_kernel(const int* __restrict__ ei, int* __restrict__ deg, int E) {
    int e = blockIdx.x * blockDim.x + threadIdx.x;
    if (e < E) atomicAdd(&deg[ei[E + e]], 1);   // dst = ei[1][e]
}

__global__ void scan_kernel(const int* __restrict__ deg, int* __restrict__ offsets, int N) {
    __shared__ int wsum[16], woff[16];
    __shared__ int carry;
    int lane = threadIdx.x & 63, w = threadIdx.x >> 6;
    if (threadIdx.x == 0) carry = 0;
    __syncthreads();
    for (int base = 0; base < N; base += 1024) {
        int i = base + (int)threadIdx.x;
        int v = (i < N) ? deg[i] : 0;
        int incl = v;
        #pragma unroll
        for (int d = 1; d < 64; d <<= 1) {
            int t = __shfl_up(incl, d, 64);
            if (lane >= d) incl += t;
        }
        if (lane == 63) wsum[w] = incl;
        __syncthreads();
        if (threadIdx.x == 0) {
            int r = carry;
            for (int k = 0; k < 16; ++k) { int t = wsum[k]; woff[k] = r; r += t; }
            carry = r;
        }
        __syncthreads();
        if (i < N) offsets[i] = woff[w] + incl - v;
        __syncthreads();
    }
    if (threadIdx.x == 0) offsets[N] = carry;
}

__global__ void scatter_kernel(const int* __restrict__ ei, const int* __restrict__ offsets,
                               int* __restrict__ cursor, int* __restrict__ csr, int E) {
    int e = blockIdx.x * blockDim.x + threadIdx.x;
    if (e < E) {
        int src = ei[e];
        int dst = ei[E + e];
        int pos = atomicAdd(&cursor[dst], 1);
        csr[offsets[dst] + pos] = src;
    }
}

// ---------------- QKV + hop-0 hidden ----------------
__global__ __launch_bounds__(256) void qkv_kernel(
    const float* __restrict__ x,
    const float* __restrict__ Wi, const float* __restrict__ bi,
    const float* __restrict__ Wq, const float* __restrict__ bq,
    const float* __restrict__ Wk, const float* __restrict__ bk,
    const float* __restrict__ Wv, const float* __restrict__ bv,
    const float* __restrict__ gam,
    float* __restrict__ Q, float* __restrict__ K0, float* __restrict__ V,
    float* __restrict__ hidden, int N)
{
    __shared__ float xs[4][F_IN];
    __shared__ float hs[4][HID];
    int w = threadIdx.x >> 6, lane = threadIdx.x & 63;
    int node = blockIdx.x * 4 + w;
    bool ok = node < N;
    if (ok) {
        xs[w][lane]      = x[(size_t)node * F_IN + lane];
        xs[w][lane + 64] = x[(size_t)node * F_IN + 64 + lane];
    }
    __syncthreads();
    float acc = bi[lane];
    #pragma unroll 8
    for (int j = 0; j < F_IN; ++j) acc += xs[w][j] * Wi[j * HID + lane];
    float hval = fmaxf(acc, 0.f);
    hs[w][lane] = hval;
    __syncthreads();
    float aq = bq[lane], ak = bk[lane], av = bv[lane];
    #pragma unroll 8
    for (int j = 0; j < HID; ++j) {
        float hj = hs[w][j];
        aq += hj * Wq[j * HID + lane];
        ak += hj * Wk[j * HID + lane];
        av += hj * Wv[j * HID + lane];
    }
    if (!ok) return;
    float qv = (aq > 0.f) ? (1.f + aq) : expf(aq);   // 1 + elu
    float kv = (ak > 0.f) ? (1.f + ak) : expf(ak);
    int h = lane >> 4;
    Q [(size_t)node * HID + lane] = qv;
    K0[(size_t)node * HID + lane] = kv;
    V [(size_t)node * HID + lane] = av;
    hidden[(size_t)node * HID + lane] = av * gam[h * 4 + 0];
}

// ---------------- K propagation + per-hop denominators ----------------
// wave per node; lane = hid dim; den[n][h] = sum_d Q*Kagg + CST
__global__ __launch_bounds__(256) void kprop_kernel(
    const float* __restrict__ Q, const float* __restrict__ Kprev,
    const int* __restrict__ offsets, const int* __restrict__ csr,
    float* __restrict__ Knext, float* __restrict__ den, int N)
{
    int lane = threadIdx.x & 63;
    int node = blockIdx.x * 4 + (threadIdx.x >> 6);
    if (node >= N) return;
    float kacc = 0.f;
    int beg = offsets[node], end = offsets[node + 1];
    for (int t = beg; t < end; ++t) {
        int s = csr[t];
        kacc += Kprev[(size_t)s * HID + lane];
    }
    if (Knext) Knext[(size_t)node * HID + lane] = kacc;
    float pd = Q[(size_t)node * HID + lane] * kacc;
    pd += __shfl_xor(pd, 1, 64);
    pd += __shfl_xor(pd, 2, 64);
    pd += __shfl_xor(pd, 4, 64);
    pd += __shfl_xor(pd, 8, 64);
    if ((lane & 15) == 0) den[(size_t)node * NH + (lane >> 4)] = pd + CSTE;
}

// ---------------- hop 1 (per head): M1 = A (Kh ⊗ Vh), hidden += ----------------
// wave per node; lane owns elements [4*lane, 4*lane+4) of the 256-elem (d,c) row
// (d = lane>>2, c0 = (lane&3)*4)
__global__ __launch_bounds__(256) void hop1h_kernel(
    const float* __restrict__ Q, const float* __restrict__ K0, const float* __restrict__ V,
    const int* __restrict__ offsets, const int* __restrict__ csr,
    const float* __restrict__ gam, const float* __restrict__ den,
    _Float16* __restrict__ M1, float* __restrict__ hidden, int N, int h)
{
    int lane = threadIdx.x & 63;
    int node = blockIdx.x * 4 + (threadIdx.x >> 6);
    if (node >= N) return;
    int d = lane >> 2, c0 = (lane & 3) * 4;
    const float* Kb = K0 + h * DD + d;
    const float* Vb = V + h * CC + c0;
    float4 acc = make_float4(0.f, 0.f, 0.f, 0.f);
    int beg = offsets[node], end = offsets[node + 1];
    for (int t = beg; t < end; ++t) {
        int s = csr[t];
        float kv = Kb[(size_t)s * HID];
        float4 v4 = *(const float4*)(Vb + (size_t)s * HID);
        acc.x += kv * v4.x; acc.y += kv * v4.y;
        acc.z += kv * v4.z; acc.w += kv * v4.w;
    }
    half4 st = { (_Float16)acc.x, (_Float16)acc.y, (_Float16)acc.z, (_Float16)acc.w };
    *(half4*)(M1 + (size_t)node * 256 + lane * 4) = st;
    float q = Q[(size_t)node * HID + h * DD + d];
    float4 p = make_float4(q * acc.x, q * acc.y, q * acc.z, q * acc.w);
    p = reduce16(p);
    if (lane < 4) {
        float dn = den[(size_t)node * NH + h];
        float g = gam[h * 4 + 1] / dn;
        float4* hp = (float4*)(hidden + (size_t)node * HID + h * CC);
        float4 cur = hp[lane];
        cur.x += g * p.x; cur.y += g * p.y; cur.z += g * p.z; cur.w += g * p.w;
        hp[lane] = cur;
    }
}

// ---------------- hops 2/3 (per head): Macc = A Mprev (+store), hidden += ----------------
__global__ __launch_bounds__(256) void hop23h_kernel(
    const float* __restrict__ Q, const _Float16* __restrict__ Mprev,
    const int* __restrict__ offsets, const int* __restrict__ csr,
    const float* __restrict__ gam, const float* __restrict__ den,
    _Float16* __restrict__ Mnext, float* __restrict__ hidden, int N, int h, int hop)
{
    int lane = threadIdx.x & 63;
    int node = blockIdx.x * 4 + (threadIdx.x >> 6);
    if (node >= N) return;
    int d = lane >> 2;
    float4 acc = make_float4(0.f, 0.f, 0.f, 0.f);
    int beg = offsets[node], end = offsets[node + 1];
    for (int t = beg; t < end; ++t) {
        int s = csr[t];
        half4 m = *(const half4*)(Mprev + (size_t)s * 256 + lane * 4);
        acc.x += (float)m.x; acc.y += (float)m.y;
        acc.z += (float)m.z; acc.w += (float)m.w;
    }
    if (Mnext) {
        half4 st = { (_Float16)acc.x, (_Float16)acc.y, (_Float16)acc.z, (_Float16)acc.w };
        *(half4*)(Mnext + (size_t)node * 256 + lane * 4) = st;
    }
    float q = Q[(size_t)node * HID + h * DD + d];
    float4 p = make_float4(q * acc.x, q * acc.y, q * acc.z, q * acc.w);
    p = reduce16(p);
    if (lane < 4) {
        float dn = den[(size_t)node * NH + h];
        float g = gam[h * 4 + hop] / dn;
        float4* hp = (float4*)(hidden + (size_t)node * HID + h * CC);
        float4 cur = hp[lane];
        cur.x += g * p.x; cur.y += g * p.y; cur.z += g * p.z; cur.w += g * p.w;
        hp[lane] = cur;
    }
}

// ---------------- output projection ----------------
__global__ __launch_bounds__(256) void out_kernel(
    const float* __restrict__ hidden, const float* __restrict__ Wo,
    const float* __restrict__ bo, float* __restrict__ out, int N)
{
    __shared__ float wo[HID * CC];
    for (int i = threadIdx.x; i < HID * CC; i += 256) wo[i] = Wo[i];
    __syncthreads();
    int idx = blockIdx.x * 256 + threadIdx.x;
    int n = idx >> 4, c = idx & 15;
    if (n >= N) return;
    float acc = bo[c];
    const float* hp = hidden + (size_t)n * HID;
    #pragma unroll 16
    for (int j = 0; j < HID; ++j) acc += hp[j] * wo[j * CC + c];
    out[(size_t)n * CC + c] = acc;
}

extern "C" void kernel_launch(void* const* d_in, const int* in_sizes, int n_in,
                              void* d_out, int out_size, void* d_ws, size_t ws_size,
                              hipStream_t stream) {
    const float* x       = (const float*)d_in[0];
    const int*   ei      = (const int*)  d_in[1];
    const float* Wi      = (const float*)d_in[2];
    const float* bi      = (const float*)d_in[3];
    const float* Wq      = (const float*)d_in[4];
    const float* bq      = (const float*)d_in[5];
    const float* Wk      = (const float*)d_in[6];
    const float* bk      = (const float*)d_in[7];
    const float* Wv      = (const float*)d_in[8];
    const float* bv      = (const float*)d_in[9];
    const float* Wo      = (const float*)d_in[10];
    const float* bo      = (const float*)d_in[11];
    const float* hopwise = (const float*)d_in[12];
    const float* temp    = (const float*)d_in[13];

    const int N = in_sizes[0] / F_IN;
    const int E = in_sizes[1] / 2;

    char* ws = (char*)d_ws;
    size_t off = 0;
    auto take = [&](size_t bytes) -> char* {
        char* p = ws + off;
        off += (bytes + 255) & ~(size_t)255;
        return p;
    };
    float*    Q      = (float*)take((size_t)N * HID * 4);
    float*    K0     = (float*)take((size_t)N * HID * 4);
    float*    V      = (float*)take((size_t)N * HID * 4);
    float*    hidden = (float*)take((size_t)N * HID * 4);
    float*    K1     = (float*)take((size_t)N * HID * 4);
    float*    K2     = (float*)take((size_t)N * HID * 4);
    float*    den1   = (float*)take((size_t)N * NH * 4);
    float*    den2   = (float*)take((size_t)N * NH * 4);
    float*    den3   = (float*)take((size_t)N * NH * 4);
    float*    gam    = (float*)take(64);
    int*      degcur = (int*)  take((size_t)2 * N * 4);   // deg | cursor
    int*      offs   = (int*)  take((size_t)(N + 1) * 4);
    int*      csr    = (int*)  take((size_t)E * 4);
    _Float16* M1     = (_Float16*)take((size_t)N * 256 * 2);
    _Float16* M2     = (_Float16*)take((size_t)N * 256 * 2);

    int* deg    = degcur;
    int* cursor = degcur + N;

    hipMemsetAsync(degcur, 0, (size_t)2 * N * 4, stream);

    gamma_kernel<<<1, 64, 0, stream>>>(hopwise, temp, gam);

    int eb = (E + 255) / 256;
    count_kernel<<<eb, 256, 0, stream>>>(ei, deg, E);
    scan_kernel<<<1, 1024, 0, stream>>>(deg, offs, N);
    scatter_kernel<<<eb, 256, 0, stream>>>(ei, offs, cursor, csr, E);

    int nb4 = (N + 3) / 4;
    qkv_kernel<<<nb4, 256, 0, stream>>>(x, Wi, bi, Wq, bq, Wk, bk, Wv, bv,
                                        gam, Q, K0, V, hidden, N);

    kprop_kernel<<<nb4, 256, 0, stream>>>(Q, K0, offs, csr, K1, den1, N);
    kprop_kernel<<<nb4, 256, 0, stream>>>(Q, K1, offs, csr, K2, den2, N);
    kprop_kernel<<<nb4, 256, 0, stream>>>(Q, K2, offs, csr, (float*)nullptr, den3, N);

    for (int h = 0; h < NH; ++h) {
        hop1h_kernel<<<nb4, 256, 0, stream>>>(Q, K0, V, offs, csr, gam, den1,
                                              M1, hidden, N, h);
        hop23h_kernel<<<nb4, 256, 0, stream>>>(Q, M1, offs, csr, gam, den2,
                                               M2, hidden, N, h, 2);
        hop23h_kernel<<<nb4, 256, 0, stream>>>(Q, M2, offs, csr, gam, den3,
                                               (_Float16*)nullptr, hidden, N, h, 3);
    }

    int ob = (N * CC + 255) / 256;
    out_kernel<<<ob, 256, 0, stream>>>(hidden, Wo, bo, (float*)d_out, N);
}

// Round 3
// 681.502 us; speedup vs baseline: 1.6120x; 1.6120x over previous
//
#include <hip/hip_runtime.h>
#include <math.h>

#define F_IN 128
#define HID  64
#define NH   4
#define DD   16
#define CC   16
#define CSTE 1e-5f

typedef _Float16 half4 __attribute__((ext_vector_type(4)));

__device__ inline float4 reduce_d(float4 p) {
    // sum across the 16 lanes with distinct d (bits 2..5 of lane)
    #pragma unroll
    for (int m = 4; m <= 32; m <<= 1) {
        p.x += __shfl_xor(p.x, m, 64);
        p.y += __shfl_xor(p.y, m, 64);
        p.z += __shfl_xor(p.z, m, 64);
        p.w += __shfl_xor(p.w, m, 64);
    }
    return p;
}

__device__ inline float reduce_d1(float v) {
    #pragma unroll
    for (int m = 4; m <= 32; m <<= 1) v += __shfl_xor(v, m, 64);
    return v;
}

// ---------------- gamma precompute (16 floats) ----------------
__global__ void gamma_kernel(const float* __restrict__ hopwise,
                             const float* __restrict__ temp,
                             float* __restrict__ gam) {
    if (threadIdx.x == 0 && blockIdx.x == 0) {
        for (int h = 0; h < NH; ++h) gam[h * 4 + 0] = temp[h * 4 + 0]; // hop0: raw temp
        for (int hop = 1; hop <= 3; ++hop) {
            float m = -1e30f;
            for (int h = 0; h < NH; ++h) m = fmaxf(m, temp[h * 4 + hop]);
            float e[NH], s = 0.f;
            for (int h = 0; h < NH; ++h) { e[h] = expf(temp[h * 4 + hop] - m); s += e[h]; }
            for (int h = 0; h < NH; ++h) gam[h * 4 + hop] = hopwise[hop] * e[h] / s;
        }
    }
}

// ---------------- CSR build ----------------
__global__ void count_kernel(const int* __restrict__ ei, int* __restrict__ deg, int E) {
    int e = blockIdx.x * blockDim.x + threadIdx.x;
    if (e < E) atomicAdd(&deg[ei[E + e]], 1);   // dst = ei[1][e]
}

__global__ void scan_kernel(const int* __restrict__ deg, int* __restrict__ offsets, int N) {
    __shared__ int wsum[16], woff[16];
    __shared__ int carry;
    int lane = threadIdx.x & 63, w = threadIdx.x >> 6;
    if (threadIdx.x == 0) carry = 0;
    __syncthreads();
    for (int base = 0; base < N; base += 4096) {
        int i0 = base + (int)threadIdx.x * 4;
        int d0 = (i0 + 0 < N) ? deg[i0 + 0] : 0;
        int d1 = (i0 + 1 < N) ? deg[i0 + 1] : 0;
        int d2 = (i0 + 2 < N) ? deg[i0 + 2] : 0;
        int d3 = (i0 + 3 < N) ? deg[i0 + 3] : 0;
        int tsum = d0 + d1 + d2 + d3;
        int incl = tsum;
        #pragma unroll
        for (int m = 1; m < 64; m <<= 1) {
            int t = __shfl_up(incl, m, 64);
            if (lane >= m) incl += t;
        }
        if (lane == 63) wsum[w] = incl;
        __syncthreads();
        if (threadIdx.x == 0) {
            int r = carry;
            for (int k = 0; k < 16; ++k) { int t = wsum[k]; woff[k] = r; r += t; }
            carry = r;
        }
        __syncthreads();
        int excl = woff[w] + incl - tsum;
        if (i0 + 0 < N) offsets[i0 + 0] = excl;
        if (i0 + 1 < N) offsets[i0 + 1] = excl + d0;
        if (i0 + 2 < N) offsets[i0 + 2] = excl + d0 + d1;
        if (i0 + 3 < N) offsets[i0 + 3] = excl + d0 + d1 + d2;
        __syncthreads();
    }
    if (threadIdx.x == 0) offsets[N] = carry;
}

__global__ void scatter_kernel(const int* __restrict__ ei, const int* __restrict__ offsets,
                               int* __restrict__ cursor, int* __restrict__ csr, int E) {
    int e = blockIdx.x * blockDim.x + threadIdx.x;
    if (e < E) {
        int src = ei[e];
        int dst = ei[E + e];
        int pos = atomicAdd(&cursor[dst], 1);
        csr[offsets[dst] + pos] = src;
    }
}

// ---------------- QKV + hop-0 hidden (16 nodes/block, 4 nodes/thread) ----------------
__global__ __launch_bounds__(256) void qkv_kernel(
    const float* __restrict__ x,
    const float* __restrict__ Wi, const float* __restrict__ bi,
    const float* __restrict__ Wq, const float* __restrict__ bq,
    const float* __restrict__ Wk, const float* __restrict__ bk,
    const float* __restrict__ Wv, const float* __restrict__ bv,
    const float* __restrict__ gam,
    float* __restrict__ Q, _Float16* __restrict__ K0h, float* __restrict__ V,
    float* __restrict__ hidden, int N)
{
    __shared__ float xs[16][F_IN];
    __shared__ float hs[16][HID];
    int t = threadIdx.x;
    int base = blockIdx.x * 16;
    {
        const float4* xg = (const float4*)(x + (size_t)base * F_IN);
        float4* xls = (float4*)&xs[0][0];
        int maxf = (min(16, N - base)) * (F_IN / 4);
        #pragma unroll
        for (int k = 0; k < 2; ++k) {
            int f = t + k * 256;
            if (f < maxf) xls[f] = xg[f];
        }
    }
    __syncthreads();
    int col = t & 63, w = t >> 6;
    float acc[4];
    #pragma unroll
    for (int i = 0; i < 4; ++i) acc[i] = bi[col];
    for (int j0 = 0; j0 < F_IN; j0 += 4) {
        float w0 = Wi[(j0 + 0) * HID + col];
        float w1 = Wi[(j0 + 1) * HID + col];
        float w2 = Wi[(j0 + 2) * HID + col];
        float w3 = Wi[(j0 + 3) * HID + col];
        #pragma unroll
        for (int i = 0; i < 4; ++i) {
            float4 xv = *(const float4*)&xs[w + 4 * i][j0];
            acc[i] += w0 * xv.x + w1 * xv.y + w2 * xv.z + w3 * xv.w;
        }
    }
    #pragma unroll
    for (int i = 0; i < 4; ++i) hs[w + 4 * i][col] = fmaxf(acc[i], 0.f);
    __syncthreads();
    float aq[4], ak[4], av[4];
    #pragma unroll
    for (int i = 0; i < 4; ++i) { aq[i] = bq[col]; ak[i] = bk[col]; av[i] = bv[col]; }
    for (int j0 = 0; j0 < HID; j0 += 4) {
        float q0 = Wq[(j0 + 0) * HID + col], k0 = Wk[(j0 + 0) * HID + col], v0 = Wv[(j0 + 0) * HID + col];
        float q1 = Wq[(j0 + 1) * HID + col], k1 = Wk[(j0 + 1) * HID + col], v1 = Wv[(j0 + 1) * HID + col];
        float q2 = Wq[(j0 + 2) * HID + col], k2 = Wk[(j0 + 2) * HID + col], v2 = Wv[(j0 + 2) * HID + col];
        float q3 = Wq[(j0 + 3) * HID + col], k3 = Wk[(j0 + 3) * HID + col], v3 = Wv[(j0 + 3) * HID + col];
        #pragma unroll
        for (int i = 0; i < 4; ++i) {
            float4 hv = *(const float4*)&hs[w + 4 * i][j0];
            aq[i] += q0 * hv.x + q1 * hv.y + q2 * hv.z + q3 * hv.w;
            ak[i] += k0 * hv.x + k1 * hv.y + k2 * hv.z + k3 * hv.w;
            av[i] += v0 * hv.x + v1 * hv.y + v2 * hv.z + v3 * hv.w;
        }
    }
    int h = col >> 4, d = col & 15;
    float g0 = gam[h * 4 + 0];
    #pragma unroll
    for (int i = 0; i < 4; ++i) {
        int node = base + w + 4 * i;
        if (node >= N) continue;
        float qv = (aq[i] > 0.f) ? (1.f + aq[i]) : expf(aq[i]);
        float kv = (ak[i] > 0.f) ? (1.f + ak[i]) : expf(ak[i]);
        Q[(size_t)node * HID + col] = qv;
        K0h[((size_t)h * N + node) * DD + d] = (_Float16)kv;
        V[(size_t)node * HID + col] = av[i];
        hidden[(size_t)node * HID + col] = av[i] * g0;
    }
}

// ---------------- hop 1 (per head): M1 = A (Kh ⊗ Vh), K1 = A K0, den, hidden += ----------------
// lane: d = lane>>2 (0..15), c0 = (lane&3)*4
__global__ __launch_bounds__(256) void hop1h_kernel(
    const float* __restrict__ Q, const _Float16* __restrict__ K0h, const float* __restrict__ V,
    const int* __restrict__ offsets, const int* __restrict__ csr,
    const float* __restrict__ gam,
    _Float16* __restrict__ M1, _Float16* __restrict__ K1h, float* __restrict__ hidden,
    int N, int h)
{
    int lane = threadIdx.x & 63;
    int node = blockIdx.x * 4 + (threadIdx.x >> 6);
    if (node >= N) return;
    int d = lane >> 2, c0 = (lane & 3) * 4;
    const _Float16* Kb = K0h + (size_t)h * N * DD + d;
    const float* Vb = V + h * CC + c0;
    float4 acc = make_float4(0.f, 0.f, 0.f, 0.f);
    float kacc = 0.f;
    int beg = offsets[node], end = offsets[node + 1];
    int t = beg;
    for (; t + 3 < end; t += 4) {
        int s0 = csr[t], s1 = csr[t + 1], s2 = csr[t + 2], s3 = csr[t + 3];
        float k0 = (float)Kb[(size_t)s0 * DD];
        float k1 = (float)Kb[(size_t)s1 * DD];
        float k2 = (float)Kb[(size_t)s2 * DD];
        float k3 = (float)Kb[(size_t)s3 * DD];
        float4 v0 = *(const float4*)(Vb + (size_t)s0 * HID);
        float4 v1 = *(const float4*)(Vb + (size_t)s1 * HID);
        float4 v2 = *(const float4*)(Vb + (size_t)s2 * HID);
        float4 v3 = *(const float4*)(Vb + (size_t)s3 * HID);
        kacc += (k0 + k1) + (k2 + k3);
        acc.x += k0 * v0.x + k1 * v1.x + k2 * v2.x + k3 * v3.x;
        acc.y += k0 * v0.y + k1 * v1.y + k2 * v2.y + k3 * v3.y;
        acc.z += k0 * v0.z + k1 * v1.z + k2 * v2.z + k3 * v3.z;
        acc.w += k0 * v0.w + k1 * v1.w + k2 * v2.w + k3 * v3.w;
    }
    for (; t < end; ++t) {
        int s = csr[t];
        float kv = (float)Kb[(size_t)s * DD];
        float4 v4 = *(const float4*)(Vb + (size_t)s * HID);
        kacc += kv;
        acc.x += kv * v4.x; acc.y += kv * v4.y;
        acc.z += kv * v4.z; acc.w += kv * v4.w;
    }
    half4 st = { (_Float16)acc.x, (_Float16)acc.y, (_Float16)acc.z, (_Float16)acc.w };
    *(half4*)(M1 + (size_t)node * 256 + lane * 4) = st;
    if ((lane & 3) == 0) K1h[((size_t)h * N + node) * DD + d] = (_Float16)kacc;
    float qd = Q[(size_t)node * HID + h * DD + d];
    float4 p = make_float4(qd * acc.x, qd * acc.y, qd * acc.z, qd * acc.w);
    p = reduce_d(p);
    float den = reduce_d1(qd * kacc) + CSTE;
    if (lane < 4) {
        float g = gam[h * 4 + 1] / den;
        float4* hp = (float4*)(hidden + (size_t)node * HID + h * CC);
        float4 cur = hp[lane];
        cur.x += g * p.x; cur.y += g * p.y; cur.z += g * p.z; cur.w += g * p.w;
        hp[lane] = cur;
    }
}

// ---------------- hops 2/3 (per head): Macc = A Mprev, Kacc = A Kprev, hidden += ----------------
__global__ __launch_bounds__(256) void hop23h_kernel(
    const float* __restrict__ Q, const _Float16* __restrict__ Mprev,
    const _Float16* __restrict__ Kprevh,
    const int* __restrict__ offsets, const int* __restrict__ csr,
    const float* __restrict__ gam,
    _Float16* __restrict__ Mnext, _Float16* __restrict__ Knexth, float* __restrict__ hidden,
    int N, int h, int hop)
{
    int lane = threadIdx.x & 63;
    int node = blockIdx.x * 4 + (threadIdx.x >> 6);
    if (node >= N) return;
    int d = lane >> 2;
    const _Float16* Kb = Kprevh + (size_t)h * N * DD + d;
    float4 acc = make_float4(0.f, 0.f, 0.f, 0.f);
    float kacc = 0.f;
    int beg = offsets[node], end = offsets[node + 1];
    int t = beg;
    for (; t + 3 < end; t += 4) {
        int s0 = csr[t], s1 = csr[t + 1], s2 = csr[t + 2], s3 = csr[t + 3];
        half4 m0 = *(const half4*)(Mprev + (size_t)s0 * 256 + lane * 4);
        half4 m1 = *(const half4*)(Mprev + (size_t)s1 * 256 + lane * 4);
        half4 m2 = *(const half4*)(Mprev + (size_t)s2 * 256 + lane * 4);
        half4 m3 = *(const half4*)(Mprev + (size_t)s3 * 256 + lane * 4);
        float k0 = (float)Kb[(size_t)s0 * DD];
        float k1 = (float)Kb[(size_t)s1 * DD];
        float k2 = (float)Kb[(size_t)s2 * DD];
        float k3 = (float)Kb[(size_t)s3 * DD];
        kacc += (k0 + k1) + (k2 + k3);
        acc.x += ((float)m0.x + (float)m1.x) + ((float)m2.x + (float)m3.x);
        acc.y += ((float)m0.y + (float)m1.y) + ((float)m2.y + (float)m3.y);
        acc.z += ((float)m0.z + (float)m1.z) + ((float)m2.z + (float)m3.z);
        acc.w += ((float)m0.w + (float)m1.w) + ((float)m2.w + (float)m3.w);
    }
    for (; t < end; ++t) {
        int s = csr[t];
        half4 m = *(const half4*)(Mprev + (size_t)s * 256 + lane * 4);
        kacc += (float)Kb[(size_t)s * DD];
        acc.x += (float)m.x; acc.y += (float)m.y;
        acc.z += (float)m.z; acc.w += (float)m.w;
    }
    if (Mnext) {
        half4 st = { (_Float16)acc.x, (_Float16)acc.y, (_Float16)acc.z, (_Float16)acc.w };
        *(half4*)(Mnext + (size_t)node * 256 + lane * 4) = st;
    }
    if (Knexth && (lane & 3) == 0)
        Knexth[((size_t)h * N + node) * DD + d] = (_Float16)kacc;
    float qd = Q[(size_t)node * HID + h * DD + d];
    float4 p = make_float4(qd * acc.x, qd * acc.y, qd * acc.z, qd * acc.w);
    p = reduce_d(p);
    float den = reduce_d1(qd * kacc) + CSTE;
    if (lane < 4) {
        float g = gam[h * 4 + hop] / den;
        float4* hp = (float4*)(hidden + (size_t)node * HID + h * CC);
        float4 cur = hp[lane];
        cur.x += g * p.x; cur.y += g * p.y; cur.z += g * p.z; cur.w += g * p.w;
        hp[lane] = cur;
    }
}

// ---------------- output projection ----------------
__global__ __launch_bounds__(256) void out_kernel(
    const float* __restrict__ hidden, const float* __restrict__ Wo,
    const float* __restrict__ bo, float* __restrict__ out, int N)
{
    __shared__ float wo[HID * CC];
    for (int i = threadIdx.x; i < HID * CC; i += 256) wo[i] = Wo[i];
    __syncthreads();
    int idx = blockIdx.x * 256 + threadIdx.x;
    int n = idx >> 4, c = idx & 15;
    if (n >= N) return;
    float acc = bo[c];
    const float4* hp4 = (const float4*)(hidden + (size_t)n * HID);
    #pragma unroll
    for (int j4 = 0; j4 < 16; ++j4) {
        float4 hv = hp4[j4];
        acc += hv.x * wo[(4 * j4 + 0) * CC + c] + hv.y * wo[(4 * j4 + 1) * CC + c]
             + hv.z * wo[(4 * j4 + 2) * CC + c] + hv.w * wo[(4 * j4 + 3) * CC + c];
    }
    out[(size_t)n * CC + c] = acc;
}

extern "C" void kernel_launch(void* const* d_in, const int* in_sizes, int n_in,
                              void* d_out, int out_size, void* d_ws, size_t ws_size,
                              hipStream_t stream) {
    const float* x       = (const float*)d_in[0];
    const int*   ei      = (const int*)  d_in[1];
    const float* Wi      = (const float*)d_in[2];
    const float* bi      = (const float*)d_in[3];
    const float* Wq      = (const float*)d_in[4];
    const float* bq      = (const float*)d_in[5];
    const float* Wk      = (const float*)d_in[6];
    const float* bk      = (const float*)d_in[7];
    const float* Wv      = (const float*)d_in[8];
    const float* bv      = (const float*)d_in[9];
    const float* Wo      = (const float*)d_in[10];
    const float* bo      = (const float*)d_in[11];
    const float* hopwise = (const float*)d_in[12];
    const float* temp    = (const float*)d_in[13];

    const int N = in_sizes[0] / F_IN;
    const int E = in_sizes[1] / 2;

    char* ws = (char*)d_ws;
    size_t off = 0;
    auto take = [&](size_t bytes) -> char* {
        char* p = ws + off;
        off += (bytes + 255) & ~(size_t)255;
        return p;
    };
    float*    Q      = (float*)take((size_t)N * HID * 4);
    float*    V      = (float*)take((size_t)N * HID * 4);
    float*    hidden = (float*)take((size_t)N * HID * 4);
    _Float16* K0h    = (_Float16*)take((size_t)NH * N * DD * 2);
    _Float16* K1h    = (_Float16*)take((size_t)NH * N * DD * 2);
    _Float16* K2h    = (_Float16*)take((size_t)NH * N * DD * 2);
    float*    gam    = (float*)take(64);
    int*      degcur = (int*)  take((size_t)2 * N * 4);   // deg | cursor
    int*      offs   = (int*)  take((size_t)(N + 1) * 4);
    int*      csr    = (int*)  take((size_t)E * 4);
    _Float16* M1     = (_Float16*)take((size_t)N * 256 * 2);
    _Float16* M2     = (_Float16*)take((size_t)N * 256 * 2);

    int* deg    = degcur;
    int* cursor = degcur + N;

    hipMemsetAsync(degcur, 0, (size_t)2 * N * 4, stream);

    gamma_kernel<<<1, 64, 0, stream>>>(hopwise, temp, gam);

    int eb = (E + 255) / 256;
    count_kernel<<<eb, 256, 0, stream>>>(ei, deg, E);
    scan_kernel<<<1, 1024, 0, stream>>>(deg, offs, N);
    scatter_kernel<<<eb, 256, 0, stream>>>(ei, offs, cursor, csr, E);

    int qb = (N + 15) / 16;
    qkv_kernel<<<qb, 256, 0, stream>>>(x, Wi, bi, Wq, bq, Wk, bk, Wv, bv,
                                       gam, Q, K0h, V, hidden, N);

    int nb4 = (N + 3) / 4;
    for (int h = 0; h < NH; ++h) {
        hop1h_kernel<<<nb4, 256, 0, stream>>>(Q, K0h, V, offs, csr, gam,
                                              M1, K1h, hidden, N, h);
        hop23h_kernel<<<nb4, 256, 0, stream>>>(Q, M1, K1h, offs, csr, gam,
                                               M2, K2h, hidden, N, h, 2);
        hop23h_kernel<<<nb4, 256, 0, stream>>>(Q, M2, K2h, offs, csr, gam,
                                               (_Float16*)nullptr, (_Float16*)nullptr,
                                               hidden, N, h, 3);
    }

    int ob = (N * CC + 255) / 256;
    out_kernel<<<ob, 256, 0, stream>>>(hidden, Wo, bo, (float*)d_out, N);
}

// Round 4
// 580.727 us; speedup vs baseline: 1.8917x; 1.1735x over previous
//
#include <hip/hip_runtime.h>
#include <math.h>

#define F_IN 128
#define HID  64
#define NH   4
#define DD   16
#define CC   16
#define CSTE 1e-5f

typedef _Float16 half4 __attribute__((ext_vector_type(4)));
typedef _Float16 half8 __attribute__((ext_vector_type(8)));

// ---------------- gamma precompute (16 floats) ----------------
__global__ void gamma_kernel(const float* __restrict__ hopwise,
                             const float* __restrict__ temp,
                             float* __restrict__ gam) {
    if (threadIdx.x == 0 && blockIdx.x == 0) {
        for (int h = 0; h < NH; ++h) gam[h * 4 + 0] = temp[h * 4 + 0]; // hop0: raw temp
        for (int hop = 1; hop <= 3; ++hop) {
            float m = -1e30f;
            for (int h = 0; h < NH; ++h) m = fmaxf(m, temp[h * 4 + hop]);
            float e[NH], s = 0.f;
            for (int h = 0; h < NH; ++h) { e[h] = expf(temp[h * 4 + hop] - m); s += e[h]; }
            for (int h = 0; h < NH; ++h) gam[h * 4 + hop] = hopwise[hop] * e[h] / s;
        }
    }
}

// ---------------- CSR build ----------------
__global__ void count_kernel(const int* __restrict__ ei, int* __restrict__ deg, int E) {
    int e = blockIdx.x * blockDim.x + threadIdx.x;
    if (e < E) atomicAdd(&deg[ei[E + e]], 1);   // dst = ei[1][e]
}

__global__ void scan_kernel(const int* __restrict__ deg, int* __restrict__ offsets, int N) {
    __shared__ int wsum[16], woff[16];
    __shared__ int carry;
    int lane = threadIdx.x & 63, w = threadIdx.x >> 6;
    if (threadIdx.x == 0) carry = 0;
    __syncthreads();
    for (int base = 0; base < N; base += 4096) {
        int i0 = base + (int)threadIdx.x * 4;
        int d0 = (i0 + 0 < N) ? deg[i0 + 0] : 0;
        int d1 = (i0 + 1 < N) ? deg[i0 + 1] : 0;
        int d2 = (i0 + 2 < N) ? deg[i0 + 2] : 0;
        int d3 = (i0 + 3 < N) ? deg[i0 + 3] : 0;
        int tsum = d0 + d1 + d2 + d3;
        int incl = tsum;
        #pragma unroll
        for (int m = 1; m < 64; m <<= 1) {
            int t = __shfl_up(incl, m, 64);
            if (lane >= m) incl += t;
        }
        if (lane == 63) wsum[w] = incl;
        __syncthreads();
        if (threadIdx.x == 0) {
            int r = carry;
            for (int k = 0; k < 16; ++k) { int t = wsum[k]; woff[k] = r; r += t; }
            carry = r;
        }
        __syncthreads();
        int excl = woff[w] + incl - tsum;
        if (i0 + 0 < N) offsets[i0 + 0] = excl;
        if (i0 + 1 < N) offsets[i0 + 1] = excl + d0;
        if (i0 + 2 < N) offsets[i0 + 2] = excl + d0 + d1;
        if (i0 + 3 < N) offsets[i0 + 3] = excl + d0 + d1 + d2;
        __syncthreads();
    }
    if (threadIdx.x == 0) offsets[N] = carry;
}

__global__ void scatter_kernel(const int* __restrict__ ei, const int* __restrict__ offsets,
                               int* __restrict__ cursor, int* __restrict__ csr, int E) {
    int e = blockIdx.x * blockDim.x + threadIdx.x;
    if (e < E) {
        int src = ei[e];
        int dst = ei[E + e];
        int pos = atomicAdd(&cursor[dst], 1);
        csr[offsets[dst] + pos] = src;
    }
}

// ---------------- QKV + hop-0 hidden (32 nodes/block, 8 nodes/thread) ----------------
__global__ __launch_bounds__(256) void qkv_kernel(
    const float* __restrict__ x,
    const float* __restrict__ Wi, const float* __restrict__ bi,
    const float* __restrict__ Wq, const float* __restrict__ bq,
    const float* __restrict__ Wk, const float* __restrict__ bk,
    const float* __restrict__ Wv, const float* __restrict__ bv,
    const float* __restrict__ gam,
    float* __restrict__ Q, _Float16* __restrict__ K0, float* __restrict__ V,
    float* __restrict__ hidden, int N)
{
    __shared__ float xs[32][F_IN];
    __shared__ float hs[32][HID];
    int t = threadIdx.x;
    int base = blockIdx.x * 32;
    {
        const float4* xg = (const float4*)(x + (size_t)base * F_IN);
        float4* xls = (float4*)&xs[0][0];
        int maxf = min(32, N - base) * (F_IN / 4);
        #pragma unroll
        for (int k = 0; k < 4; ++k) {
            int f = t + k * 256;
            if (f < maxf) xls[f] = xg[f];
        }
    }
    __syncthreads();
    int col = t & 63, w = t >> 6;
    float acc[8];
    #pragma unroll
    for (int i = 0; i < 8; ++i) acc[i] = bi[col];
    for (int j0 = 0; j0 < F_IN; j0 += 4) {
        float w0 = Wi[(j0 + 0) * HID + col];
        float w1 = Wi[(j0 + 1) * HID + col];
        float w2 = Wi[(j0 + 2) * HID + col];
        float w3 = Wi[(j0 + 3) * HID + col];
        #pragma unroll
        for (int i = 0; i < 8; ++i) {
            float4 xv = *(const float4*)&xs[w + 4 * i][j0];
            acc[i] += w0 * xv.x + w1 * xv.y + w2 * xv.z + w3 * xv.w;
        }
    }
    #pragma unroll
    for (int i = 0; i < 8; ++i) hs[w + 4 * i][col] = fmaxf(acc[i], 0.f);
    __syncthreads();
    float aq[8], ak[8], av[8];
    #pragma unroll
    for (int i = 0; i < 8; ++i) { aq[i] = bq[col]; ak[i] = bk[col]; av[i] = bv[col]; }
    for (int j0 = 0; j0 < HID; j0 += 4) {
        float q0 = Wq[(j0 + 0) * HID + col], k0 = Wk[(j0 + 0) * HID + col], v0 = Wv[(j0 + 0) * HID + col];
        float q1 = Wq[(j0 + 1) * HID + col], k1 = Wk[(j0 + 1) * HID + col], v1 = Wv[(j0 + 1) * HID + col];
        float q2 = Wq[(j0 + 2) * HID + col], k2 = Wk[(j0 + 2) * HID + col], v2 = Wv[(j0 + 2) * HID + col];
        float q3 = Wq[(j0 + 3) * HID + col], k3 = Wk[(j0 + 3) * HID + col], v3 = Wv[(j0 + 3) * HID + col];
        #pragma unroll
        for (int i = 0; i < 8; ++i) {
            float4 hv = *(const float4*)&hs[w + 4 * i][j0];
            aq[i] += q0 * hv.x + q1 * hv.y + q2 * hv.z + q3 * hv.w;
            ak[i] += k0 * hv.x + k1 * hv.y + k2 * hv.z + k3 * hv.w;
            av[i] += v0 * hv.x + v1 * hv.y + v2 * hv.z + v3 * hv.w;
        }
    }
    int h = col >> 4;
    float g0 = gam[h * 4 + 0];
    #pragma unroll
    for (int i = 0; i < 8; ++i) {
        int node = base + w + 4 * i;
        if (node >= N) continue;
        float qv = (aq[i] > 0.f) ? (1.f + aq[i]) : expf(aq[i]);
        float kv = (ak[i] > 0.f) ? (1.f + ak[i]) : expf(ak[i]);
        Q [(size_t)node * 64 + col] = qv;
        K0[(size_t)node * 64 + col] = (_Float16)kv;
        V [(size_t)node * 64 + col] = av[i];
        hidden[(size_t)node * 64 + col] = av[i] * g0;
    }
}

// ---------------- shared epilogue: Q-scale, reduce-scatter over d, hidden += ----------------
// lane = h*16 + p. u[j] holds column (p^j) for this lane's d=p (XOR-permuted layout).
// After butterfly, u[0] = sum_d Q_d * M[d][p] — lane p owns output column c=p.
__device__ __forceinline__ void hop_epilogue(
    float* u, float qd, float kacc, const float* gam,
    float* __restrict__ hidden, int node, int lane, int hop)
{
    #pragma unroll
    for (int j = 0; j < 16; ++j) u[j] *= qd;
    #pragma unroll
    for (int m = 1; m < 16; m <<= 1) {
        #pragma unroll
        for (int j = 0; j < 16; ++j) {
            if ((j & (2 * m - 1)) == 0) u[j] += __shfl_xor(u[j | m], m, 64);
        }
    }
    float kq = qd * kacc;
    kq += __shfl_xor(kq, 1, 64);
    kq += __shfl_xor(kq, 2, 64);
    kq += __shfl_xor(kq, 4, 64);
    kq += __shfl_xor(kq, 8, 64);
    float g = gam[(lane >> 4) * 4 + hop] / (kq + CSTE);
    hidden[(size_t)node * 64 + lane] += g * u[0];
}

// ---------------- fast hop 1: all heads, M1 = A (K ⊗ V), K1 = A K0, hidden += ----------------
__global__ __launch_bounds__(256) void hop1_all(
    const float* __restrict__ Q, const _Float16* __restrict__ K0, const float* __restrict__ V,
    const int* __restrict__ offsets, const int* __restrict__ csr,
    const float* __restrict__ gam,
    _Float16* __restrict__ M1, _Float16* __restrict__ K1, float* __restrict__ hidden, int N)
{
    int lane = threadIdx.x & 63;
    int node = blockIdx.x * 4 + (threadIdx.x >> 6);
    if (node >= N) return;
    int p = lane & 15;      // d within head
    int hb = lane & 48;     // h*16
    float u[16];
    #pragma unroll
    for (int j = 0; j < 16; ++j) u[j] = 0.f;
    float kacc = 0.f;
    int beg = offsets[node], end = offsets[node + 1];
    int t = beg;
    for (; t + 1 < end; t += 2) {
        int s0 = csr[t], s1 = csr[t + 1];
        float v0 = V[(size_t)s0 * 64 + lane];
        float v1 = V[(size_t)s1 * 64 + lane];
        float k0 = (float)K0[(size_t)s0 * 64 + lane];
        float k1 = (float)K0[(size_t)s1 * 64 + lane];
        kacc += k0 + k1;
        #pragma unroll
        for (int j = 0; j < 16; ++j) {
            int srcl = hb + (p ^ j);
            u[j] += k0 * __shfl(v0, srcl, 64) + k1 * __shfl(v1, srcl, 64);
        }
    }
    for (; t < end; ++t) {
        int s = csr[t];
        float vv = V[(size_t)s * 64 + lane];
        float kk = (float)K0[(size_t)s * 64 + lane];
        kacc += kk;
        #pragma unroll
        for (int j = 0; j < 16; ++j)
            u[j] += kk * __shfl(vv, hb + (p ^ j), 64);
    }
    // store M1 (XOR-permuted columns), K1
    half8* mp = (half8*)(M1 + (size_t)node * 1024 + lane * 16);
    half8 s0h, s1h;
    #pragma unroll
    for (int j = 0; j < 8; ++j) { s0h[j] = (_Float16)u[j]; s1h[j] = (_Float16)u[8 + j]; }
    mp[0] = s0h; mp[1] = s1h;
    K1[(size_t)node * 64 + lane] = (_Float16)kacc;
    float qd = Q[(size_t)node * 64 + lane];
    hop_epilogue(u, qd, kacc, gam, hidden, node, lane, 1);
}

// ---------------- fast hops 2/3: all heads, Macc = A Mprev, Kacc = A Kprev ----------------
template<bool STORE>
__global__ __launch_bounds__(256) void hop23_all(
    const float* __restrict__ Q, const _Float16* __restrict__ Mprev,
    const _Float16* __restrict__ Kprev,
    const int* __restrict__ offsets, const int* __restrict__ csr,
    const float* __restrict__ gam,
    _Float16* __restrict__ Mnext, _Float16* __restrict__ Knext,
    float* __restrict__ hidden, int N, int hop)
{
    int lane = threadIdx.x & 63;
    int node = blockIdx.x * 4 + (threadIdx.x >> 6);
    if (node >= N) return;
    float u[16];
    #pragma unroll
    for (int j = 0; j < 16; ++j) u[j] = 0.f;
    float kacc = 0.f;
    int beg = offsets[node], end = offsets[node + 1];
    int t = beg;
    for (; t + 1 < end; t += 2) {
        int s0 = csr[t], s1 = csr[t + 1];
        const half8* a = (const half8*)(Mprev + (size_t)s0 * 1024 + lane * 16);
        const half8* b = (const half8*)(Mprev + (size_t)s1 * 1024 + lane * 16);
        half8 a0 = a[0], a1 = a[1], b0 = b[0], b1 = b[1];
        float ka = (float)Kprev[(size_t)s0 * 64 + lane];
        float kb = (float)Kprev[(size_t)s1 * 64 + lane];
        kacc += ka + kb;
        #pragma unroll
        for (int j = 0; j < 8; ++j) {
            u[j]     += (float)a0[j] + (float)b0[j];
            u[8 + j] += (float)a1[j] + (float)b1[j];
        }
    }
    for (; t < end; ++t) {
        int s = csr[t];
        const half8* a = (const half8*)(Mprev + (size_t)s * 1024 + lane * 16);
        half8 a0 = a[0], a1 = a[1];
        kacc += (float)Kprev[(size_t)s * 64 + lane];
        #pragma unroll
        for (int j = 0; j < 8; ++j) {
            u[j]     += (float)a0[j];
            u[8 + j] += (float)a1[j];
        }
    }
    if (STORE) {
        half8* mp = (half8*)(Mnext + (size_t)node * 1024 + lane * 16);
        half8 s0h, s1h;
        #pragma unroll
        for (int j = 0; j < 8; ++j) { s0h[j] = (_Float16)u[j]; s1h[j] = (_Float16)u[8 + j]; }
        mp[0] = s0h; mp[1] = s1h;
        Knext[(size_t)node * 64 + lane] = (_Float16)kacc;
    }
    float qd = Q[(size_t)node * 64 + lane];
    hop_epilogue(u, qd, kacc, gam, hidden, node, lane, hop);
}

// ================ fallback per-head hop kernels (round-3 structure, K in [n][64]) ================
__device__ inline float4 reduce_d(float4 p) {
    #pragma unroll
    for (int m = 4; m <= 32; m <<= 1) {
        p.x += __shfl_xor(p.x, m, 64);
        p.y += __shfl_xor(p.y, m, 64);
        p.z += __shfl_xor(p.z, m, 64);
        p.w += __shfl_xor(p.w, m, 64);
    }
    return p;
}
__device__ inline float reduce_d1(float v) {
    #pragma unroll
    for (int m = 4; m <= 32; m <<= 1) v += __shfl_xor(v, m, 64);
    return v;
}

__global__ __launch_bounds__(256) void hop1h_kernel(
    const float* __restrict__ Q, const _Float16* __restrict__ K0, const float* __restrict__ V,
    const int* __restrict__ offsets, const int* __restrict__ csr,
    const float* __restrict__ gam,
    _Float16* __restrict__ M1, _Float16* __restrict__ K1, float* __restrict__ hidden,
    int N, int h)
{
    int lane = threadIdx.x & 63;
    int node = blockIdx.x * 4 + (threadIdx.x >> 6);
    if (node >= N) return;
    int d = lane >> 2, c0 = (lane & 3) * 4;
    const _Float16* Kb = K0 + h * 16 + d;
    const float* Vb = V + h * CC + c0;
    float4 acc = make_float4(0.f, 0.f, 0.f, 0.f);
    float kacc = 0.f;
    int beg = offsets[node], end = offsets[node + 1];
    for (int t = beg; t < end; ++t) {
        int s = csr[t];
        float kv = (float)Kb[(size_t)s * 64];
        float4 v4 = *(const float4*)(Vb + (size_t)s * HID);
        kacc += kv;
        acc.x += kv * v4.x; acc.y += kv * v4.y;
        acc.z += kv * v4.z; acc.w += kv * v4.w;
    }
    half4 st = { (_Float16)acc.x, (_Float16)acc.y, (_Float16)acc.z, (_Float16)acc.w };
    *(half4*)(M1 + (size_t)node * 256 + lane * 4) = st;
    if ((lane & 3) == 0) K1[(size_t)node * 64 + h * 16 + d] = (_Float16)kacc;
    float qd = Q[(size_t)node * 64 + h * 16 + d];
    float4 p = make_float4(qd * acc.x, qd * acc.y, qd * acc.z, qd * acc.w);
    p = reduce_d(p);
    float den = reduce_d1(qd * kacc) + CSTE;
    if (lane < 4) {
        float g = gam[h * 4 + 1] / den;
        float4* hp = (float4*)(hidden + (size_t)node * 64 + h * CC);
        float4 cur = hp[lane];
        cur.x += g * p.x; cur.y += g * p.y; cur.z += g * p.z; cur.w += g * p.w;
        hp[lane] = cur;
    }
}

__global__ __launch_bounds__(256) void hop23h_kernel(
    const float* __restrict__ Q, const _Float16* __restrict__ Mprev,
    const _Float16* __restrict__ Kprev,
    const int* __restrict__ offsets, const int* __restrict__ csr,
    const float* __restrict__ gam,
    _Float16* __restrict__ Mnext, _Float16* __restrict__ Knext, float* __restrict__ hidden,
    int N, int h, int hop)
{
    int lane = threadIdx.x & 63;
    int node = blockIdx.x * 4 + (threadIdx.x >> 6);
    if (node >= N) return;
    int d = lane >> 2;
    const _Float16* Kb = Kprev + h * 16 + d;
    float4 acc = make_float4(0.f, 0.f, 0.f, 0.f);
    float kacc = 0.f;
    int beg = offsets[node], end = offsets[node + 1];
    for (int t = beg; t < end; ++t) {
        int s = csr[t];
        half4 m = *(const half4*)(Mprev + (size_t)s * 256 + lane * 4);
        kacc += (float)Kb[(size_t)s * 64];
        acc.x += (float)m.x; acc.y += (float)m.y;
        acc.z += (float)m.z; acc.w += (float)m.w;
    }
    if (Mnext) {
        half4 st = { (_Float16)acc.x, (_Float16)acc.y, (_Float16)acc.z, (_Float16)acc.w };
        *(half4*)(Mnext + (size_t)node * 256 + lane * 4) = st;
        if ((lane & 3) == 0) Knext[(size_t)node * 64 + h * 16 + d] = (_Float16)kacc;
    }
    float qd = Q[(size_t)node * 64 + h * 16 + d];
    float4 p = make_float4(qd * acc.x, qd * acc.y, qd * acc.z, qd * acc.w);
    p = reduce_d(p);
    float den = reduce_d1(qd * kacc) + CSTE;
    if (lane < 4) {
        float g = gam[h * 4 + hop] / den;
        float4* hp = (float4*)(hidden + (size_t)node * 64 + h * CC);
        float4 cur = hp[lane];
        cur.x += g * p.x; cur.y += g * p.y; cur.z += g * p.z; cur.w += g * p.w;
        hp[lane] = cur;
    }
}

// ---------------- output projection ----------------
__global__ __launch_bounds__(256) void out_kernel(
    const float* __restrict__ hidden, const float* __restrict__ Wo,
    const float* __restrict__ bo, float* __restrict__ out, int N)
{
    __shared__ float wo[HID * CC];
    for (int i = threadIdx.x; i < HID * CC; i += 256) wo[i] = Wo[i];
    __syncthreads();
    int idx = blockIdx.x * 256 + threadIdx.x;
    int n = idx >> 4, c = idx & 15;
    if (n >= N) return;
    float acc = bo[c];
    const float4* hp4 = (const float4*)(hidden + (size_t)n * HID);
    #pragma unroll
    for (int j4 = 0; j4 < 16; ++j4) {
        float4 hv = hp4[j4];
        acc += hv.x * wo[(4 * j4 + 0) * CC + c] + hv.y * wo[(4 * j4 + 1) * CC + c]
             + hv.z * wo[(4 * j4 + 2) * CC + c] + hv.w * wo[(4 * j4 + 3) * CC + c];
    }
    out[(size_t)n * CC + c] = acc;
}

extern "C" void kernel_launch(void* const* d_in, const int* in_sizes, int n_in,
                              void* d_out, int out_size, void* d_ws, size_t ws_size,
                              hipStream_t stream) {
    const float* x       = (const float*)d_in[0];
    const int*   ei      = (const int*)  d_in[1];
    const float* Wi      = (const float*)d_in[2];
    const float* bi      = (const float*)d_in[3];
    const float* Wq      = (const float*)d_in[4];
    const float* bq      = (const float*)d_in[5];
    const float* Wk      = (const float*)d_in[6];
    const float* bk      = (const float*)d_in[7];
    const float* Wv      = (const float*)d_in[8];
    const float* bv      = (const float*)d_in[9];
    const float* Wo      = (const float*)d_in[10];
    const float* bo      = (const float*)d_in[11];
    const float* hopwise = (const float*)d_in[12];
    const float* temp    = (const float*)d_in[13];

    const int N = in_sizes[0] / F_IN;
    const int E = in_sizes[1] / 2;

    char* ws = (char*)d_ws;
    size_t off = 0;
    auto take = [&](size_t bytes) -> char* {
        char* p = ws + off;
        off += (bytes + 255) & ~(size_t)255;
        return p;
    };
    float*    Q      = (float*)take((size_t)N * 64 * 4);
    float*    V      = (float*)take((size_t)N * 64 * 4);
    float*    hidden = (float*)take((size_t)N * 64 * 4);
    _Float16* K0     = (_Float16*)take((size_t)N * 64 * 2);
    _Float16* K1     = (_Float16*)take((size_t)N * 64 * 2);
    _Float16* K2     = (_Float16*)take((size_t)N * 64 * 2);
    float*    gam    = (float*)take(64);
    int*      degcur = (int*)  take((size_t)2 * N * 4);   // deg | cursor
    int*      offs   = (int*)  take((size_t)(N + 1) * 4);
    int*      csr    = (int*)  take((size_t)E * 4);

    // fast path needs 2 × all-head fp16 M buffers (N*1024 halfs each)
    size_t fast_need = off + 2 * (((size_t)N * 1024 * 2 + 255) & ~(size_t)255) + 4096;
    bool fast = (ws_size >= fast_need);

    int* deg    = degcur;
    int* cursor = degcur + N;

    hipMemsetAsync(degcur, 0, (size_t)2 * N * 4, stream);

    gamma_kernel<<<1, 64, 0, stream>>>(hopwise, temp, gam);

    int eb = (E + 255) / 256;
    count_kernel<<<eb, 256, 0, stream>>>(ei, deg, E);
    scan_kernel<<<1, 1024, 0, stream>>>(deg, offs, N);
    scatter_kernel<<<eb, 256, 0, stream>>>(ei, offs, cursor, csr, E);

    int qb = (N + 31) / 32;
    qkv_kernel<<<qb, 256, 0, stream>>>(x, Wi, bi, Wq, bq, Wk, bk, Wv, bv,
                                       gam, Q, K0, V, hidden, N);

    int nb4 = (N + 3) / 4;
    if (fast) {
        _Float16* M1 = (_Float16*)take((size_t)N * 1024 * 2);
        _Float16* M2 = (_Float16*)take((size_t)N * 1024 * 2);
        hop1_all<<<nb4, 256, 0, stream>>>(Q, K0, V, offs, csr, gam, M1, K1, hidden, N);
        hop23_all<true ><<<nb4, 256, 0, stream>>>(Q, M1, K1, offs, csr, gam, M2, K2, hidden, N, 2);
        hop23_all<false><<<nb4, 256, 0, stream>>>(Q, M2, K2, offs, csr, gam,
                                                  (_Float16*)nullptr, (_Float16*)nullptr,
                                                  hidden, N, 3);
    } else {
        _Float16* M1 = (_Float16*)take((size_t)N * 256 * 2);
        _Float16* M2 = (_Float16*)take((size_t)N * 256 * 2);
        for (int h = 0; h < NH; ++h) {
            hop1h_kernel<<<nb4, 256, 0, stream>>>(Q, K0, V, offs, csr, gam,
                                                  M1, K1, hidden, N, h);
            hop23h_kernel<<<nb4, 256, 0, stream>>>(Q, M1, K1, offs, csr, gam,
                                                   M2, K2, hidden, N, h, 2);
            hop23h_kernel<<<nb4, 256, 0, stream>>>(Q, M2, K2, offs, csr, gam,
                                                   (_Float16*)nullptr, (_Float16*)nullptr,
                                                   hidden, N, h, 3);
        }
    }

    int ob = (N * CC + 255) / 256;
    out_kernel<<<ob, 256, 0, stream>>>(hidden, Wo, bo, (float*)d_out, N);
}